// Round 1
// baseline (1054.978 us; speedup 1.0000x reference)
//
#include <hip/hip_runtime.h>

typedef _Float16 h8v __attribute__((ext_vector_type(8)));
typedef _Float16 h4v __attribute__((ext_vector_type(4)));
typedef float f4v __attribute__((ext_vector_type(4)));

#define NEGF (-3.4028234663852886e38f)

// ---------------- cast hidden fp32 -> fp16 ----------------
__global__ __launch_bounds__(256) void cast_hs_kernel(const float* __restrict__ in,
                                                      _Float16* __restrict__ out) {
  int i = (blockIdx.x * 256 + threadIdx.x) * 4;
  float4 v = *(const float4*)(in + i);
  h4v o = {(_Float16)v.x, (_Float16)v.y, (_Float16)v.z, (_Float16)v.w};
  *(h4v*)(out + i) = o;
}

// ---------------- weight transpose+cast: W fp32 [K][N] -> Wt fp16 [N][K] ----------------
__global__ __launch_bounds__(256) void wtrans_kernel(const float* __restrict__ W,
                                                     _Float16* __restrict__ Wt) {
  __shared__ float tile[32][33];
  int tx = threadIdx.x & 31, ty = threadIdx.x >> 5;
  int c0 = blockIdx.x * 32;  // n
  int r0 = blockIdx.y * 32;  // k
  for (int i = 0; i < 4; i++)
    tile[ty + i * 8][tx] = W[(size_t)(r0 + ty + i * 8) * 4096 + c0 + tx];
  __syncthreads();
  for (int i = 0; i < 4; i++)
    Wt[(size_t)(c0 + ty + i * 8) * 4096 + r0 + tx] = (_Float16)tile[tx][ty + i * 8];
}

// ---------------- GEMM: A[1920][4096] fp16  x  Bt[4096(N)][4096(K)] fp16 ----------------
// 128x128 tile, 4 waves (2x2), each wave 64x64 via 4x4 mfma_f32_16x16x32_f16 frags.
// LDS layout [kchunk(4)][row(128)][8]: conflict-free b128 frag reads, contiguous chunk writes.
template <typename OutT, bool HEAD_LAYOUT>
__global__ __launch_bounds__(256) void gemm_kernel(const _Float16* __restrict__ A,
                                                   const _Float16* __restrict__ Bt,
                                                   OutT* __restrict__ C) {
  const int K = 4096, N = 4096;
  int m0 = blockIdx.y * 128, n0 = blockIdx.x * 128;
  __shared__ __align__(16) _Float16 As[4096];
  __shared__ __align__(16) _Float16 Bs[4096];
  int t = threadIdx.x;
  int lane = t & 63, w = t >> 6, quad = lane >> 4, l16 = lane & 15;
  int wm = (w >> 1) * 64, wn = (w & 1) * 64;
  f4v acc[4][4] = {};
  int c_a = t >> 7;   // chunk c for i=0 (0..1); i=1 handles c+2
  int mr = t & 127;
  const _Float16* Arow0 = A + (size_t)(m0 + mr) * K + c_a * 8;
  const _Float16* Arow1 = Arow0 + 16;
  const _Float16* Brow0 = Bt + (size_t)(n0 + mr) * K + c_a * 8;
  const _Float16* Brow1 = Brow0 + 16;
  for (int kk = 0; kk < K; kk += 32) {
    __syncthreads();
    *(uint4*)(As + t * 8)         = *(const uint4*)(Arow0 + kk);
    *(uint4*)(As + (t + 256) * 8) = *(const uint4*)(Arow1 + kk);
    *(uint4*)(Bs + t * 8)         = *(const uint4*)(Brow0 + kk);
    *(uint4*)(Bs + (t + 256) * 8) = *(const uint4*)(Brow1 + kk);
    __syncthreads();
    h8v af[4], bf[4];
    for (int mi = 0; mi < 4; mi++)
      af[mi] = *(const h8v*)(As + (quad * 128 + wm + mi * 16 + l16) * 8);
    for (int ni = 0; ni < 4; ni++)
      bf[ni] = *(const h8v*)(Bs + (quad * 128 + wn + ni * 16 + l16) * 8);
    for (int mi = 0; mi < 4; mi++)
      for (int ni = 0; ni < 4; ni++)
        acc[mi][ni] = __builtin_amdgcn_mfma_f32_16x16x32_f16(af[mi], bf[ni], acc[mi][ni], 0, 0, 0);
  }
  for (int mi = 0; mi < 4; mi++)
    for (int ni = 0; ni < 4; ni++) {
      int col = n0 + wn + ni * 16 + l16;
      for (int rr = 0; rr < 4; rr++) {
        int row = m0 + wm + mi * 16 + quad * 4 + rr;  // D: row=(lane>>4)*4+reg, col=lane&15
        size_t oidx;
        if (HEAD_LAYOUT) {
          int b = row >= 960 ? 1 : 0;
          int q = row - b * 960;
          oidx = ((size_t)(b * 32 + (col >> 7)) * 960 + q) * 128 + (col & 127);
        } else {
          oidx = (size_t)row * N + col;
        }
        C[oidx] = (OutT)acc[mi][ni][rr];
      }
    }
}

// ---------------- in-place RoPE on [bh][q][128] fp16 ----------------
__global__ __launch_bounds__(256) void rope_kernel(_Float16* __restrict__ x) {
  int idx = blockIdx.x * 256 + threadIdx.x;
  int d = idx & 63;
  int rest = idx >> 6;        // bh*960 + q
  int q = rest % 960;
  size_t base = (size_t)rest * 128 + d;
  float x1 = (float)x[base], x2 = (float)x[base + 64];
  float invf = exp2f((float)d * -0.20762050593046016f);  // 10000^(-d/64)
  float ang = (float)q * invf;
  float c = cosf(ang), s = sinf(ang);
  x[base]      = (_Float16)(x1 * c - x2 * s);
  x[base + 64] = (_Float16)(x2 * c + x1 * s);
}

// ---------------- V transpose per head: [bh][q][d] -> [bh][d][q] ----------------
__global__ __launch_bounds__(256) void vtrans_kernel(const _Float16* __restrict__ in,
                                                     _Float16* __restrict__ vt) {
  __shared__ _Float16 tile[32][33];
  int tx = threadIdx.x & 31, ty = threadIdx.x >> 5;
  int q0 = blockIdx.x * 32;
  int d0 = blockIdx.y * 32;
  int bh = blockIdx.z;
  for (int i = 0; i < 4; i++)
    tile[ty + i * 8][tx] = in[((size_t)bh * 960 + q0 + ty + i * 8) * 128 + d0 + tx];
  __syncthreads();
  for (int i = 0; i < 4; i++)
    vt[((size_t)bh * 128 + d0 + ty + i * 8) * 960 + q0 + tx] = tile[tx][ty + i * 8];
}

// ---------------- fused landmark attention ----------------
// grid (60 qtiles, 64 bh), 256 threads. 16 q-rows per block, full-k S row in LDS.
__global__ __launch_bounds__(256) void attn_kernel(const _Float16* __restrict__ qr,
                                                   const _Float16* __restrict__ kr,
                                                   const _Float16* __restrict__ vt,
                                                   _Float16* __restrict__ attn_out) {
  const int qt = blockIdx.x;
  const int bh = blockIdx.y;
  const int b = bh >> 5, h = bh & 31;
  const int q0 = qt * 16;
  const int qb = q0 >> 6;     // current 64-block index; landmarks at 64j+63
  const int t = threadIdx.x;
  const int w = t >> 6, lane = t & 63, quad = lane >> 4, l16 = lane & 15;

  __shared__ __align__(16) float S[16][968];
  __shared__ float Mg[16][16];
  __shared__ float Dg[16][16];
  __shared__ float LMg[16][16];

  // Q fragments (A-operand: m=lane&15 row, k=quad*8+j)
  const _Float16* qbase = qr + (size_t)(bh * 960 + q0) * 128;
  h8v qf[4];
  for (int dc = 0; dc < 4; dc++)
    qf[dc] = *(const h8v*)(qbase + l16 * 128 + dc * 32 + quad * 8);

  // Phase 1: S[q][k] for k < 64*(qb+1), causal-masked, scaled
  const float rscale = 0.08838834764831845f;  // 1/sqrt(128)
  for (int kt = 0; kt <= qb; kt++) {
    int kc0 = kt * 64 + w * 16;
    const _Float16* kbase = kr + (size_t)(bh * 960 + kc0 + l16) * 128;
    f4v acc = {0.f, 0.f, 0.f, 0.f};
    for (int dc = 0; dc < 4; dc++) {
      h8v kf = *(const h8v*)(kbase + dc * 32 + quad * 8);  // B-op: n=lane&15 (k-col), k=d
      acc = __builtin_amdgcn_mfma_f32_16x16x32_f16(qf[dc], kf, acc, 0, 0, 0);
    }
    int kcol = kc0 + l16;
    for (int r = 0; r < 4; r++) {
      int m = quad * 4 + r;
      S[m][kcol] = (kcol <= q0 + m) ? acc[r] * rscale : NEGF;
    }
  }
  __syncthreads();

  // Phase 2: per (row, group) max + exp-sum. group g<qb: 63 non-mem of block g.
  // group 15: current block (64) + prior landmarks (qb).
  {
    int r = t >> 4, g = t & 15;
    if (g == 15) {
      int cb = qb * 64;
      float mx = NEGF;
      for (int j = 0; j < 64; j++) mx = fmaxf(mx, S[r][cb + ((j + r) & 63)]);
      for (int j2 = 0; j2 < qb; j2++) mx = fmaxf(mx, S[r][j2 * 64 + 63]);
      float dsum = 0.f;
      for (int j = 0; j < 64; j++) dsum += expf(S[r][cb + ((j + r) & 63)] - mx);
      for (int j2 = 0; j2 < qb; j2++) dsum += expf(S[r][j2 * 64 + 63] - mx);
      Mg[r][15] = mx; Dg[r][15] = dsum;
    } else if (g < qb) {
      int base = g * 64;
      float mx = NEGF;
      for (int j = 0; j < 63; j++) {
        int jj = j + g; if (jj >= 63) jj -= 63;   // bank stagger
        mx = fmaxf(mx, S[r][base + jj]);
      }
      float dsum = 0.f;
      for (int j = 0; j < 63; j++) {
        int jj = j + g; if (jj >= 63) jj -= 63;
        dsum += expf(S[r][base + jj] - mx);
      }
      Mg[r][g] = mx; Dg[r][g] = dsum;
    }
  }
  __syncthreads();

  // Phase 3: landmark gate per prior group
  {
    int r = t >> 4, g = t & 15;
    if (g < qb)
      LMg[r][g] = expf(S[r][g * 64 + 63] - Mg[r][15]) / Dg[r][15];
  }
  __syncthreads();

  // Phase 4: final weights, in place
  {
    int r = t >> 4, c0 = t & 15;
    float M15 = Mg[r][15];
    float iD15 = 1.f / Dg[r][15];
    int kmax = (qb + 1) * 64;
    for (int k = c0; k < kmax; k += 16) {
      int g = k >> 6;
      float wgt;
      if (g == qb)             wgt = expf(S[r][k] - M15) * iD15;   // current block (incl. its landmark)
      else if ((k & 63) == 63) wgt = 0.f;                          // foreign landmark
      else                     wgt = expf(S[r][k] - Mg[r][g]) / Dg[r][g] * LMg[r][g];
      S[r][k] = wgt;
    }
  }
  __syncthreads();

  // Phase 5: PV. wave w -> d columns [w*32, w*32+32)
  {
    int d0 = w * 32;
    const _Float16* vbase = vt + (size_t)(bh * 128 + d0) * 960;
    f4v oacc[2] = {{0.f, 0.f, 0.f, 0.f}, {0.f, 0.f, 0.f, 0.f}};
    int nkc = (qb + 1) * 2;
    for (int kc = 0; kc < nkc; kc++) {
      int k0 = kc * 32 + quad * 8;
      float4 wa = *(const float4*)&S[l16][k0];
      float4 wb = *(const float4*)&S[l16][k0 + 4];
      h8v af = {(_Float16)wa.x, (_Float16)wa.y, (_Float16)wa.z, (_Float16)wa.w,
                (_Float16)wb.x, (_Float16)wb.y, (_Float16)wb.z, (_Float16)wb.w};
      for (int nt = 0; nt < 2; nt++) {
        h8v bfv = *(const h8v*)(vbase + (nt * 16 + l16) * 960 + k0);
        oacc[nt] = __builtin_amdgcn_mfma_f32_16x16x32_f16(af, bfv, oacc[nt], 0, 0, 0);
      }
    }
    for (int nt = 0; nt < 2; nt++)
      for (int rr = 0; rr < 4; rr++) {
        int qrow = q0 + quad * 4 + rr;
        int col = h * 128 + d0 + nt * 16 + l16;
        attn_out[(size_t)(b * 960 + qrow) * 4096 + col] = (_Float16)oacc[nt][rr];
      }
  }
}

extern "C" void kernel_launch(void* const* d_in, const int* in_sizes, int n_in,
                              void* d_out, int out_size, void* d_ws, size_t ws_size,
                              hipStream_t stream) {
  (void)in_sizes; (void)n_in; (void)out_size; (void)ws_size;
  const float* hs = (const float*)d_in[0];
  const float* wq = (const float*)d_in[1];
  const float* wk = (const float*)d_in[2];
  const float* wv = (const float*)d_in[3];
  const float* wo = (const float*)d_in[4];
  char* ws = (char*)d_ws;
  _Float16* wt   = (_Float16*)(ws);                 // 33,554,432 B
  _Float16* hsf  = (_Float16*)(ws + 33554432ull);   // 15,728,640 B (also attn_out alias)
  _Float16* qr   = (_Float16*)(ws + 49283072ull);   // 15,728,640 B
  _Float16* kr   = (_Float16*)(ws + 65011712ull);   // 15,728,640 B
  _Float16* vtmp = (_Float16*)(ws + 80740352ull);   // 15,728,640 B
  _Float16* vt   = (_Float16*)(ws + 96468992ull);   // 15,728,640 B  (total 112,197,632 B)
  _Float16* attn = hsf;   // hsf dead after V GEMM
  float* out = (float*)d_out;

  hipLaunchKernelGGL(cast_hs_kernel, dim3(7680), dim3(256), 0, stream, hs, hsf);

  // Q
  hipLaunchKernelGGL(wtrans_kernel, dim3(128, 128), dim3(256), 0, stream, wq, wt);
  hipLaunchKernelGGL((gemm_kernel<_Float16, true>), dim3(32, 15), dim3(256), 0, stream, hsf, wt, qr);
  hipLaunchKernelGGL(rope_kernel, dim3(15360), dim3(256), 0, stream, qr);
  // K
  hipLaunchKernelGGL(wtrans_kernel, dim3(128, 128), dim3(256), 0, stream, wk, wt);
  hipLaunchKernelGGL((gemm_kernel<_Float16, true>), dim3(32, 15), dim3(256), 0, stream, hsf, wt, kr);
  hipLaunchKernelGGL(rope_kernel, dim3(15360), dim3(256), 0, stream, kr);
  // V
  hipLaunchKernelGGL(wtrans_kernel, dim3(128, 128), dim3(256), 0, stream, wv, wt);
  hipLaunchKernelGGL((gemm_kernel<_Float16, true>), dim3(32, 15), dim3(256), 0, stream, hsf, wt, vtmp);
  hipLaunchKernelGGL(vtrans_kernel, dim3(30, 4, 64), dim3(256), 0, stream, vtmp, vt);
  // attention
  hipLaunchKernelGGL(attn_kernel, dim3(60, 64), dim3(256), 0, stream, qr, kr, vt, attn);
  // O
  hipLaunchKernelGGL(wtrans_kernel, dim3(128, 128), dim3(256), 0, stream, wo, wt);
  hipLaunchKernelGGL((gemm_kernel<float, false>), dim3(32, 15), dim3(256), 0, stream, attn, wt, out);
}